// Round 8
// baseline (323.831 us; speedup 1.0000x reference)
//
#include <hip/hip_runtime.h>
#include <stdint.h>

#define B_    4
#define CIN   32
#define NN    1024
#define SS    32
#define COUT  64
#define CSP   64
#define EPSV  1e-5f

__device__ __forceinline__ uint32_t f2b_rne(float f) {
    uint32_t x = __float_as_uint(f);
    return (x + 0x7fffu + ((x >> 16) & 1u)) >> 16;
}

// ---------- graph prep ----------
__global__ void detect_kernel(const int* __restrict__ ei, int* __restrict__ flag) {
    if (threadIdx.x == 0) {
        int nz = 0;
        for (int i = 1; i < 257; i += 2) nz |= ei[i];
        *flag = (nz == 0) ? 1 : 0;   // 1 => int64 layout
    }
}

__global__ void deg_count_kernel(const int* __restrict__ ei, int E,
                                 const int* __restrict__ flag, int* __restrict__ deg) {
    int e = blockIdx.x * 256 + threadIdx.x;
    int i64 = *flag;
    if (e < E) {
        int d = i64 ? ei[2 * (E + e)] : ei[E + e];
        atomicAdd(&deg[d], 1);
    }
}

__global__ __launch_bounds__(1024) void scan_kernel(
    const int* __restrict__ deg, int* __restrict__ row_ptr, float* __restrict__ dinv) {
    __shared__ int sb[NN];
    int t = threadIdx.x;
    int v = deg[t];
    sb[t] = v;
    __syncthreads();
    for (int off = 1; off < NN; off <<= 1) {
        int tmp = (t >= off) ? sb[t - off] : 0;
        __syncthreads();
        sb[t] += tmp;
        __syncthreads();
    }
    row_ptr[t] = sb[t] - v;                 // exclusive scan
    if (t == NN - 1) row_ptr[NN] = sb[t];
    dinv[t] = rsqrtf((float)(v + 1));       // +1 self-loop
}

// Packed edge descriptors: {srcn, dinv[srcn]}
__global__ void csr_fill_kernel(const int* __restrict__ ei, int E,
                                const int* __restrict__ flag,
                                const int* __restrict__ row_ptr, int* __restrict__ cursor,
                                const float* __restrict__ dinv, int2* __restrict__ edata) {
    int e = blockIdx.x * 256 + threadIdx.x;
    int i64 = *flag;
    if (e < E) {
        int s = i64 ? ei[2 * e] : ei[e];
        int d = i64 ? ei[2 * (E + e)] : ei[E + e];
        int pos = atomicAdd(&cursor[d], 1);
        edata[row_ptr[d] + pos] = make_int2(s, __float_as_int(dinv[s]));
    }
}

// ---------- temporal conv1: 8n/block, 4cout x 8s per thread, wave = n ----------
__global__ __launch_bounds__(512, 4) void conv1_kernel(
    const float* __restrict__ x, const float* __restrict__ W1,
    const float* __restrict__ b1, float* __restrict__ h_pre,
    float* __restrict__ psum, float* __restrict__ pss) {
    __shared__ __align__(16) float pool[15360];    // xs[32*288] | w1l[96*64] = 61.4 KB
    float* xs  = pool;                             // [cin][n*36 + s], halo 0 at [32],[35]
    float* w1l = pool + 9216;                      // [kk][cout] (transposed)
    int t = threadIdx.x;
    int grp = blockIdx.x;                          // 512 = b(4) x ngrp(128)
    int b = grp >> 7, n0 = (grp & 127) * 8;
    {   // W1[cout][96] -> w1l[kk][cout]
        int cout = t >> 3, kkb = (t & 7) * 12;
        const float* wsrc = W1 + cout * 96 + kkb;
#pragma unroll
        for (int j = 0; j < 12; j++) w1l[(kkb + j) * 64 + cout] = wsrc[j];
    }
    if (t < 256) {                                 // halo zeros (slots 32..35)
        float* p = xs + (t >> 3) * 288 + (t & 7) * 36 + 32;
        p[0] = 0.f; p[1] = 0.f; p[2] = 0.f; p[3] = 0.f;
    }
#pragma unroll
    for (int i = 0; i < 4; i++) {                  // stage x: 1 KB contiguous per wave
        int flat4 = i * 512 + t;
        int cin = flat4 >> 6;
        int rem = flat4 & 63;
        int n = rem >> 3, s4 = (rem & 7) * 4;
        float4 v = *(const float4*)(x + (((size_t)b * CIN + cin) * NN + n0 + n) * SS + s4);
        *(float4*)(xs + cin * 288 + n * 36 + s4) = v;
    }
    __syncthreads();
    int lane = t & 63, wvi = t >> 6;
    int n = wvi;                                   // one n per wave
    int cout0 = 4 * (lane & 15), s0 = 8 * ((lane >> 4) & 3);
    int m1 = (s0 == 0) ? 35 : (s0 - 1);            // left halo lives at [35]
    float y[4][8];
#pragma unroll
    for (int cc = 0; cc < 4; cc++) {
        float bbv = b1[cout0 + cc];
#pragma unroll
        for (int j = 0; j < 8; j++) y[cc][j] = bbv;
    }
#pragma unroll 4
    for (int cin = 0; cin < CIN; cin++) {
        const float* xr = xs + cin * 288 + n * 36;
        float xw[10];
        xw[0] = xr[m1];
        float4 xa = *(const float4*)(xr + s0);
        float4 xb = *(const float4*)(xr + s0 + 4);
        xw[1] = xa.x; xw[2] = xa.y; xw[3] = xa.z; xw[4] = xa.w;
        xw[5] = xb.x; xw[6] = xb.y; xw[7] = xb.z; xw[8] = xb.w;
        xw[9] = xr[s0 + 8];
        const float* wb = w1l + (3 * cin) * 64 + cout0;
        float4 w0 = *(const float4*)(wb);
        float4 w1v = *(const float4*)(wb + 64);
        float4 w2v = *(const float4*)(wb + 128);
        float wk0[4] = {w0.x, w0.y, w0.z, w0.w};
        float wk1[4] = {w1v.x, w1v.y, w1v.z, w1v.w};
        float wk2[4] = {w2v.x, w2v.y, w2v.z, w2v.w};
#pragma unroll
        for (int cc = 0; cc < 4; cc++)
#pragma unroll
            for (int j = 0; j < 8; j++)
                y[cc][j] += wk0[cc] * xw[j] + wk1[cc] * xw[j + 1] + wk2[cc] * xw[j + 2];
    }
    float* hb = h_pre + (((size_t)(b * NN + n0 + n)) * COUT + cout0) * SS + s0;
#pragma unroll
    for (int cc = 0; cc < 4; cc++) {
        float4 o0 = {y[cc][0], y[cc][1], y[cc][2], y[cc][3]};
        float4 o1 = {y[cc][4], y[cc][5], y[cc][6], y[cc][7]};
        *(float4*)(hb + cc * SS) = o0;
        *(float4*)(hb + cc * SS + 4) = o1;
    }
    float aS[4], aQ[4];
#pragma unroll
    for (int cc = 0; cc < 4; cc++) {
        float s_ = 0.f, q_ = 0.f;
#pragma unroll
        for (int j = 0; j < 8; j++) { s_ += y[cc][j]; q_ += y[cc][j] * y[cc][j]; }
        s_ += __shfl_down(s_, 16); s_ += __shfl_down(s_, 32);
        q_ += __shfl_down(q_, 16); q_ += __shfl_down(q_, 32);
        aS[cc] = s_; aQ[cc] = q_;
    }
    __syncthreads();                               // xs dead -> reuse pool as red
    float* redS = pool;
    float* redQ = pool + 512;
    if (lane < 16) {
#pragma unroll
        for (int cc = 0; cc < 4; cc++) {
            redS[wvi * 64 + 4 * lane + cc] = aS[cc];
            redQ[wvi * 64 + 4 * lane + cc] = aQ[cc];
        }
    }
    __syncthreads();
    if (t < 64) {
        float S = 0.f, Q = 0.f;
#pragma unroll
        for (int w = 0; w < 8; w++) { S += redS[w * 64 + t]; Q += redQ[w * 64 + t]; }
        psum[t * 512 + grp] = S;
        pss[t * 512 + grp] = Q;
    }
}

// ---------- reduce per-block partials -> scale/shift ----------
__global__ void bn_reduce_kernel(const float* __restrict__ psum, const float* __restrict__ pss,
                                 const float* __restrict__ g, const float* __restrict__ be,
                                 float* __restrict__ scale, float* __restrict__ shift,
                                 float invM, int stride, int nslots) {
    int c = blockIdx.x, t = threadIdx.x;    // 64 blocks x 256 threads
    const float* ps = psum + c * stride;
    const float* pq = pss + c * stride;
    float s = 0.f, q = 0.f;
    for (int i = t; i < nslots; i += 256) { s += ps[i]; q += pq[i]; }
#pragma unroll
    for (int o = 32; o > 0; o >>= 1) { s += __shfl_down(s, o); q += __shfl_down(q, o); }
    __shared__ float ws_[4], wq_[4];
    if ((t & 63) == 0) { ws_[t >> 6] = s; wq_[t >> 6] = q; }
    __syncthreads();
    if (t == 0) {
        float S = ws_[0] + ws_[1] + ws_[2] + ws_[3];
        float Q = wq_[0] + wq_[1] + wq_[2] + wq_[3];
        float m = S * invM, v = Q * invM - m * m;
        float sc = g[c] * rsqrtf(v + EPSV);
        scale[c] = sc;
        shift[c] = be[c] - m * sc;
    }
}

// ---------- BN1 apply + ReLU + (h · Wg) -> hw bf16 [B,S,N,Csp]; 4n/block ----------
__global__ __launch_bounds__(256, 2) void bn1_gemm_kernel(
    const float* __restrict__ h_pre, const float* __restrict__ scale1,
    const float* __restrict__ shift1, const float* __restrict__ Wg,
    ushort* __restrict__ hw) {
    __shared__ __align__(16) float hs[COUT * 144];  // [c][n*36+s], 36.9 KB
    __shared__ __align__(16) float wgl[COUT * CSP]; // 16.4 KB
    int t = threadIdx.x;
    int grp = blockIdx.x;                           // 1024 = b(4) x 256
    int b = grp >> 8, n0 = (grp & 255) * 4;
#pragma unroll
    for (int i = 0; i < 4; i++)
        ((float4*)wgl)[i * 256 + t] = ((const float4*)Wg)[i * 256 + t];
#pragma unroll
    for (int i = 0; i < 8; i++) {
        int flat4 = i * 256 + t;
        int n = flat4 >> 9;
        int rem = flat4 & 511;
        int c = rem >> 3, s4 = (rem & 7) * 4;
        float sc1 = scale1[c], sh1 = shift1[c];
        const float* p = h_pre + (((size_t)(b * NN + n0 + n)) * COUT + c) * SS + s4;
        float4 u = *(const float4*)p;
        float4 v;
        v.x = fmaxf(u.x * sc1 + sh1, 0.f);
        v.y = fmaxf(u.y * sc1 + sh1, 0.f);
        v.z = fmaxf(u.z * sc1 + sh1, 0.f);
        v.w = fmaxf(u.w * sc1 + sh1, 0.f);
        *(float4*)(hs + c * 144 + n * 36 + s4) = v;
    }
    __syncthreads();
    int lane = t & 63, n = t >> 6;
    int d0 = 4 * (lane & 15), s0 = 8 * ((lane >> 4) & 3);
    float acc[4][8];
#pragma unroll
    for (int cc = 0; cc < 4; cc++)
#pragma unroll
        for (int j = 0; j < 8; j++) acc[cc][j] = 0.f;
#pragma unroll 4
    for (int c = 0; c < COUT; c++) {
        float4 w4 = *(const float4*)(wgl + c * 64 + d0);
        const float* xr = hs + c * 144 + n * 36;
        float4 xa = *(const float4*)(xr + s0);
        float4 xb = *(const float4*)(xr + s0 + 4);
        float xv[8] = {xa.x, xa.y, xa.z, xa.w, xb.x, xb.y, xb.z, xb.w};
#pragma unroll
        for (int j = 0; j < 8; j++) {
            acc[0][j] += xv[j] * w4.x;
            acc[1][j] += xv[j] * w4.y;
            acc[2][j] += xv[j] * w4.z;
            acc[3][j] += xv[j] * w4.w;
        }
    }
#pragma unroll
    for (int j = 0; j < 8; j++) {
        uint32_t p0 = f2b_rne(acc[0][j]) | (f2b_rne(acc[1][j]) << 16);
        uint32_t p1 = f2b_rne(acc[2][j]) | (f2b_rne(acc[3][j]) << 16);
        uint2 o = {p0, p1};
        *(uint2*)(hw + (((size_t)(b * SS + s0 + j)) * NN + n0 + n) * CSP + d0) = o;
    }
}

// ---------- GCN aggregate v2: LDS-resident slice quarter, LDS edge chunks ----------
// One block per (bs slice, channel quarter). 1024 threads = 16 waves, 64 dst nodes/wave.
// Per wave-round: 4 edges x 16 channels; descriptors broadcast via ds_read_b64.
__global__ __launch_bounds__(1024, 8) void gcn_kernel(
    const ushort* __restrict__ hw, const int* __restrict__ row_ptr,
    const int2* __restrict__ edata, const float* __restrict__ dinv,
    const float* __restrict__ bg, float* __restrict__ agg,
    float* __restrict__ sum2, float* __restrict__ ss2) {
    __shared__ ushort sl[NN * 16];          // 32 KB: slice quarter (bf16)
    __shared__ int2 ebuf[16][64];           // 8 KB: per-wave edge chunks
    __shared__ float red[16][16][2];        // 2 KB: stats partials
    int t = threadIdx.x;
    int blk = blockIdx.x;                   // 512 = 8 xcd x 16 slices x 4 quarters
    int xcd = blk & 7, idx = blk >> 3;
    int bs = xcd * 16 + (idx >> 2);
    int q = idx & 3;
    int b = bs >> 5, s = bs & 31;
    const ushort* hws = hw + (size_t)bs * NN * 64 + q * 16;
#pragma unroll
    for (int i = 0; i < 4; i++) {           // stage slice quarter, coalesced 8B ops
        int j = i * 1024 + t;
        int n = j >> 2, c4 = (j & 3) * 4;
        *(uint2*)(&sl[n * 16 + c4]) = *(const uint2*)(hws + (size_t)n * 64 + c4);
    }
    __syncthreads();
    int w = t >> 6, lane = t & 63;
    int c = lane & 15, j4 = lane >> 4;      // channel, edge sub-slot
    int nStart = w * 64;
    int rp = row_ptr[nStart + lane];        // node ptrs prefetched to lanes
    int rEndW = row_ptr[nStart + 64];
    float dv = dinv[nStart + lane];
    float bgf = bg[q * 16 + c];
    int2* eb = ebuf[w];
    int cb = -(1 << 20);                    // forces first refill
    float sSum = 0.f, sSq = 0.f;
    for (int ni = 0; ni < 64; ni++) {
        int n = nStart + ni;
        int rn0 = __shfl(rp, ni);
        int rn1 = (ni < 63) ? __shfl(rp, ni + 1) : rEndW;
        float dn = __shfl(dv, ni);
        float acc = 0.f;
        int r = rn0;
        while (r + 4 <= rn1) {              // full rounds: 4 edges, no guards
            if (r + 3 >= cb + 64) {         // wave-uniform refill (overread lands in ws pad)
                cb = r;
                eb[lane] = edata[cb + lane];
            }
            int2 e = eb[r - cb + j4];       // 4 broadcast descriptors
            float xv = __uint_as_float((uint32_t)sl[e.x * 16 + c] << 16);
            acc += __int_as_float(e.y) * xv;
            r += 4;
        }
        int rem = rn1 - r;                  // 0..3 tail edges
        if (rem > 0) {
            if (r + 3 >= cb + 64) { cb = r; eb[lane] = edata[cb + lane]; }
            int kk = r - cb + ((j4 < rem) ? j4 : 0);
            int2 e = eb[kk];
            float wt = (j4 < rem) ? __int_as_float(e.y) : 0.f;
            float xv = __uint_as_float((uint32_t)sl[e.x * 16 + c] << 16);
            acc += wt * xv;
        }
        acc += __shfl_xor(acc, 16);         // combine 4 edge sub-slots
        acc += __shfl_xor(acc, 32);
        if (lane < 16) {
            float selfv = __uint_as_float((uint32_t)sl[n * 16 + c] << 16);
            float v = dn * (acc + dn * selfv) + bgf;
            agg[(((size_t)(b * NN + n)) * SS + s) * 64 + q * 16 + c] = v;
            sSum += v; sSq += v * v;
        }
    }
    if (lane < 16) { red[w][c][0] = sSum; red[w][c][1] = sSq; }
    __syncthreads();
    if (t < 16) {                           // exact stats for (bs, q*16+t): no atomics
        float S = 0.f, Q = 0.f;
#pragma unroll
        for (int ww = 0; ww < 16; ww++) { S += red[ww][t][0]; Q += red[ww][t][1]; }
        sum2[bs * 64 + q * 16 + t] = S;
        ss2[bs * 64 + q * 16 + t] = Q;
    }
}

__global__ void bn2_finalize_kernel(const float* __restrict__ sum2, const float* __restrict__ ss2,
                                    const float* __restrict__ gs, const float* __restrict__ bes,
                                    float* __restrict__ scale2, float* __restrict__ shift2) {
    int idx = blockIdx.x * 256 + threadIdx.x;   // 8192 = B*S*Csp
    int d = idx & 63;
    float m = sum2[idx] * (1.f / NN);
    float v = ss2[idx] * (1.f / NN) - m * m;
    float sc = gs[d] * rsqrtf(v + EPSV);
    scale2[idx] = sc;
    shift2[idx] = bes[d] - m * sc;
}

// ---------- BN2+ReLU + conv2: 8n/block, cin-halved LDS, reg accumulators ----------
__global__ __launch_bounds__(512, 4) void conv2_kernel(
    const float* __restrict__ agg, const float* __restrict__ scale2,
    const float* __restrict__ shift2, const float* __restrict__ W2,
    const float* __restrict__ b2, float* __restrict__ h2_pre,
    float* __restrict__ psum, float* __restrict__ pss) {
    __shared__ __align__(16) float pool[15360];    // ts[32*288] | w2l[96*64] = 61.4 KB
    float* ts  = pool;                             // [cinL][n*36+s]
    float* w2l = pool + 9216;                      // [kkL][cout]
    int t = threadIdx.x;
    int grp = blockIdx.x;                          // 512 = b(4) x ngrp(128)
    int b = grp >> 7, n0 = (grp & 127) * 8;
    int s_st = (t >> 3) & 31;                      // staging s (const per thread)
    int c4_st = t & 7;                             // staging c-quad
    if (t < 256) {                                 // halo zeros (persist across halves)
        float* p = ts + (t >> 3) * 288 + (t & 7) * 36 + 32;
        p[0] = 0.f; p[1] = 0.f; p[2] = 0.f; p[3] = 0.f;
    }
    int lane = t & 63, wvi = t >> 6;
    int n = wvi;
    int cout0 = 4 * (lane & 15), s0 = 8 * ((lane >> 4) & 3);
    int m1 = (s0 == 0) ? 35 : (s0 - 1);
    float y[4][8];
#pragma unroll
    for (int cc = 0; cc < 4; cc++) {
        float bbv = b2[cout0 + cc];
#pragma unroll
        for (int j = 0; j < 8; j++) y[cc][j] = bbv;
    }
    for (int half = 0; half < 2; half++) {
        __syncthreads();                           // prev compute done / halos published
        {   // stage weight half: kk in [half*96, half*96+96)
            int cout = t >> 3, kkb = (t & 7) * 12;
            const float* wsrc = W2 + cout * 192 + half * 96 + kkb;
#pragma unroll
            for (int j = 0; j < 12; j++) w2l[(kkb + j) * 64 + cout] = wsrc[j];
        }
        {   // stage activation half from agg[B,N,S,C] with BN2+ReLU
            int c0 = half * 32 + 4 * c4_st;
            int bsi = b * SS + s_st;
            float4 sc = *(const float4*)(scale2 + bsi * 64 + c0);
            float4 sh = *(const float4*)(shift2 + bsi * 64 + c0);
            int cL = 4 * c4_st;
#pragma unroll
            for (int i = 0; i < 4; i++) {
                int nn_ = 2 * i + (t >> 8);
                float4 u = *(const float4*)(agg +
                    (((size_t)(b * NN + n0 + nn_)) * SS + s_st) * CSP + c0);
                float* dst = ts + cL * 288 + nn_ * 36 + s_st;
                dst[0]   = fmaxf(u.x * sc.x + sh.x, 0.f);
                dst[288] = fmaxf(u.y * sc.y + sh.y, 0.f);
                dst[576] = fmaxf(u.z * sc.z + sh.z, 0.f);
                dst[864] = fmaxf(u.w * sc.w + sh.w, 0.f);
            }
        }
        __syncthreads();
#pragma unroll 4
        for (int cl = 0; cl < 32; cl++) {
            const float* xr = ts + cl * 288 + n * 36;
            float xw[10];
            xw[0] = xr[m1];
            float4 xa = *(const float4*)(xr + s0);
            float4 xb = *(const float4*)(xr + s0 + 4);
            xw[1] = xa.x; xw[2] = xa.y; xw[3] = xa.z; xw[4] = xa.w;
            xw[5] = xb.x; xw[6] = xb.y; xw[7] = xb.z; xw[8] = xb.w;
            xw[9] = xr[s0 + 8];
            const float* wb = w2l + (3 * cl) * 64 + cout0;
            float4 w0 = *(const float4*)(wb);
            float4 w1v = *(const float4*)(wb + 64);
            float4 w2v = *(const float4*)(wb + 128);
            float wk0[4] = {w0.x, w0.y, w0.z, w0.w};
            float wk1[4] = {w1v.x, w1v.y, w1v.z, w1v.w};
            float wk2[4] = {w2v.x, w2v.y, w2v.z, w2v.w};
#pragma unroll
            for (int cc = 0; cc < 4; cc++)
#pragma unroll
                for (int j = 0; j < 8; j++)
                    y[cc][j] += wk0[cc] * xw[j] + wk1[cc] * xw[j + 1] + wk2[cc] * xw[j + 2];
        }
    }
    float* hb = h2_pre + (((size_t)(b * NN + n0 + n)) * COUT + cout0) * SS + s0;
#pragma unroll
    for (int cc = 0; cc < 4; cc++) {
        float4 o0 = {y[cc][0], y[cc][1], y[cc][2], y[cc][3]};
        float4 o1 = {y[cc][4], y[cc][5], y[cc][6], y[cc][7]};
        *(float4*)(hb + cc * SS) = o0;
        *(float4*)(hb + cc * SS + 4) = o1;
    }
    float aS[4], aQ[4];
#pragma unroll
    for (int cc = 0; cc < 4; cc++) {
        float s_ = 0.f, q_ = 0.f;
#pragma unroll
        for (int j = 0; j < 8; j++) { s_ += y[cc][j]; q_ += y[cc][j] * y[cc][j]; }
        s_ += __shfl_down(s_, 16); s_ += __shfl_down(s_, 32);
        q_ += __shfl_down(q_, 16); q_ += __shfl_down(q_, 32);
        aS[cc] = s_; aQ[cc] = q_;
    }
    __syncthreads();                               // ts dead -> reuse pool
    float* redS = pool;
    float* redQ = pool + 512;
    if (lane < 16) {
#pragma unroll
        for (int cc = 0; cc < 4; cc++) {
            redS[wvi * 64 + 4 * lane + cc] = aS[cc];
            redQ[wvi * 64 + 4 * lane + cc] = aQ[cc];
        }
    }
    __syncthreads();
    if (t < 64) {
        float S = 0.f, Q = 0.f;
#pragma unroll
        for (int w = 0; w < 8; w++) { S += redS[w * 64 + t]; Q += redQ[w * 64 + t]; }
        psum[t * 512 + grp] = S;
        pss[t * 512 + grp] = Q;
    }
}

// ---------- final: BN3+ReLU + residual 1x1 conv + ReLU, write [B,Cout,N,S] ----------
__global__ __launch_bounds__(256) void final_kernel(
    const float* __restrict__ x, const float* __restrict__ Wres,
    const float* __restrict__ bres, const float* __restrict__ h2_pre,
    const float* __restrict__ scale3, const float* __restrict__ shift3,
    float* __restrict__ out) {
    __shared__ __align__(16) float xs[CIN][36];
    __shared__ float wrl[COUT * 33];
    int t = threadIdx.x;
    int bn = blockIdx.x;
    int b = bn >> 10, n = bn & (NN - 1);
    {
        int sst = t & 31, cinb = t >> 5;            // bank 2-way
#pragma unroll
        for (int i = 0; i < 4; i++) {
            int cin = cinb + 8 * i;
            xs[cin][sst] = x[(((size_t)b * CIN + cin) * NN + n) * SS + sst];
        }
    }
#pragma unroll
    for (int i = 0; i < 2; i++) {
        int lin = (i * 256 + t) * 4;                // rows of 32
        int cw = lin >> 5, c0 = lin & 31;
        float4 v = *(const float4*)(Wres + lin);
        float* dst = &wrl[cw * 33 + c0];
        dst[0] = v.x; dst[1] = v.y; dst[2] = v.z; dst[3] = v.w;
    }
    __syncthreads();
    int cout = t >> 2, s0 = (t & 3) * 8;
    float res[8];
    float bb = bres[cout];
#pragma unroll
    for (int j = 0; j < 8; j++) res[j] = bb;
    const float* wrow = &wrl[cout * 33];
#pragma unroll 4
    for (int cin = 0; cin < CIN; cin++) {
        float w = wrow[cin];
        float4 xa = *(const float4*)&xs[cin][s0];
        float4 xb = *(const float4*)&xs[cin][s0 + 4];
        res[0] += xa.x * w; res[1] += xa.y * w; res[2] += xa.z * w; res[3] += xa.w * w;
        res[4] += xb.x * w; res[5] += xb.y * w; res[6] += xb.z * w; res[7] += xb.w * w;
    }
    const float* hp = h2_pre + (size_t)bn * COUT * SS + cout * SS + s0;
    float4 h0 = *(const float4*)hp, h1 = *(const float4*)(hp + 4);
    float h2[8] = {h0.x, h0.y, h0.z, h0.w, h1.x, h1.y, h1.z, h1.w};
    float sc = scale3[cout], sh = shift3[cout];
    float o[8];
#pragma unroll
    for (int j = 0; j < 8; j++) {
        float hv = fmaxf(sc * h2[j] + sh, 0.f);
        o[j] = fmaxf(hv + res[j], 0.f);
    }
    float* op = out + (((size_t)b * COUT + cout) * NN + n) * SS + s0;
    float4 o0 = {o[0], o[1], o[2], o[3]}, o1 = {o[4], o[5], o[6], o[7]};
    *(float4*)op = o0; *(float4*)(op + 4) = o1;
}

// ---------- host ----------
extern "C" void kernel_launch(void* const* d_in, const int* in_sizes, int n_in,
                              void* d_out, int out_size, void* d_ws, size_t ws_size,
                              hipStream_t stream) {
    const float* x    = (const float*)d_in[0];
    const int*   ei   = (const int*)  d_in[1];
    const float* W1   = (const float*)d_in[2];
    const float* b1   = (const float*)d_in[3];
    const float* g1   = (const float*)d_in[4];
    const float* be1  = (const float*)d_in[5];
    const float* Wg   = (const float*)d_in[6];
    const float* bg   = (const float*)d_in[7];
    const float* gs   = (const float*)d_in[8];
    const float* bes  = (const float*)d_in[9];
    const float* W2   = (const float*)d_in[10];
    const float* b2   = (const float*)d_in[11];
    const float* g2   = (const float*)d_in[12];
    const float* be2  = (const float*)d_in[13];
    const float* Wres = (const float*)d_in[14];
    const float* bres = (const float*)d_in[15];
    float* out = (float*)d_out;
    int E = in_sizes[1] / 2;

    char* ws = (char*)d_ws;
    // zeroed region: [0, 8192)
    int*   deg    = (int*)  (ws + 0);            // 4096 B
    int*   cursor = (int*)  (ws + 4096);         // 4096 B
    float* sum2   = (float*)(ws + 8192);         // 32768 B (written fully by gcn)
    float* ssq2   = (float*)(ws + 40960);        // 32768 B
    int*   row_ptr= (int*)  (ws + 73728);        // 4100 B
    int*   flag   = (int*)  (ws + 77888);        // 4 B
    float* dinv   = (float*)(ws + 78080);        // 4096 B
    float* scale1 = (float*)(ws + 82176);        // 256 B each
    float* shift1 = (float*)(ws + 82432);
    float* scale3 = (float*)(ws + 82688);
    float* shift3 = (float*)(ws + 82944);
    float* scale2 = (float*)(ws + 83200);        // 32768 B
    float* shift2 = (float*)(ws + 115968);       // 32768 B -> 148736
    float* psum   = (float*)(ws + 148736);       // 131072 B (64 ch x 512 slots)
    float* pss    = (float*)(ws + 279808);       // 131072 B -> 410880
    int2*  edata  = (int2*) (ws + 410880);       // 8*E = 131072 B -> 541952 (+768 pad)
    float* bigA   = (float*)(ws + 542720);       // 33.55 MB: hw(bf16), then h2_pre(fp32)
    // d_out doubles as scratch: h_pre (conv1 out), then agg (gcn out).
    float* h_pre  = out;
    float* agg    = out;
    ushort* hwB   = (ushort*)bigA;

    hipMemsetAsync(ws, 0, 8192, stream);
    detect_kernel<<<1, 64, 0, stream>>>(ei, flag);
    int egrid = (E + 255) / 256;
    deg_count_kernel<<<egrid, 256, 0, stream>>>(ei, E, flag, deg);
    scan_kernel<<<1, NN, 0, stream>>>(deg, row_ptr, dinv);
    csr_fill_kernel<<<egrid, 256, 0, stream>>>(ei, E, flag, row_ptr, cursor, dinv, edata);

    conv1_kernel<<<512, 512, 0, stream>>>(x, W1, b1, h_pre, psum, pss);
    bn_reduce_kernel<<<64, 256, 0, stream>>>(psum, pss, g1, be1, scale1, shift1,
                                             1.f / (B_ * NN * SS), 512, 512);
    bn1_gemm_kernel<<<1024, 256, 0, stream>>>(h_pre, scale1, shift1, Wg, hwB);
    gcn_kernel<<<512, 1024, 0, stream>>>(hwB, row_ptr, edata, dinv, bg, agg, sum2, ssq2);
    bn2_finalize_kernel<<<32, 256, 0, stream>>>(sum2, ssq2, gs, bes, scale2, shift2);
    conv2_kernel<<<512, 512, 0, stream>>>(agg, scale2, shift2, W2, b2, bigA, psum, pss);
    bn_reduce_kernel<<<64, 256, 0, stream>>>(psum, pss, g2, be2, scale3, shift3,
                                             1.f / (B_ * NN * SS), 512, 512);
    final_kernel<<<B_ * NN, 256, 0, stream>>>(x, Wres, bres, bigA, scale3, shift3, out);
}

// Round 9
// 281.287 us; speedup vs baseline: 1.1512x; 1.1512x over previous
//
#include <hip/hip_runtime.h>
#include <stdint.h>

#define B_    4
#define CIN   32
#define NN    1024
#define SS    32
#define COUT  64
#define CSP   64
#define EPSV  1e-5f

__device__ __forceinline__ uint32_t f2b_rne(float f) {
    uint32_t x = __float_as_uint(f);
    return (x + 0x7fffu + ((x >> 16) & 1u)) >> 16;
}
__device__ __forceinline__ float bfu(uint32_t v) { return __uint_as_float(v << 16); }
__device__ __forceinline__ float bfh(uint32_t v) { return __uint_as_float(v & 0xffff0000u); }

// ---------- graph prep ----------
__global__ void detect_kernel(const int* __restrict__ ei, int* __restrict__ flag) {
    if (threadIdx.x == 0) {
        int nz = 0;
        for (int i = 1; i < 257; i += 2) nz |= ei[i];
        *flag = (nz == 0) ? 1 : 0;   // 1 => int64 layout
    }
}

__global__ void deg_count_kernel(const int* __restrict__ ei, int E,
                                 const int* __restrict__ flag, int* __restrict__ deg) {
    int e = blockIdx.x * 256 + threadIdx.x;
    int i64 = *flag;
    if (e < E) {
        int d = i64 ? ei[2 * (E + e)] : ei[E + e];
        atomicAdd(&deg[d], 1);
    }
}

__global__ __launch_bounds__(1024) void scan_kernel(
    const int* __restrict__ deg, int* __restrict__ row_ptr, float* __restrict__ dinv) {
    __shared__ int sb[NN];
    int t = threadIdx.x;
    int v = deg[t];
    sb[t] = v;
    __syncthreads();
    for (int off = 1; off < NN; off <<= 1) {
        int tmp = (t >= off) ? sb[t - off] : 0;
        __syncthreads();
        sb[t] += tmp;
        __syncthreads();
    }
    row_ptr[t] = sb[t] - v;                 // exclusive scan
    if (t == NN - 1) row_ptr[NN] = sb[t];
    dinv[t] = rsqrtf((float)(v + 1));       // +1 self-loop
}

// Packed edge descriptors: {srcn, dinv[srcn]}
__global__ void csr_fill_kernel(const int* __restrict__ ei, int E,
                                const int* __restrict__ flag,
                                const int* __restrict__ row_ptr, int* __restrict__ cursor,
                                const float* __restrict__ dinv, int2* __restrict__ edata) {
    int e = blockIdx.x * 256 + threadIdx.x;
    int i64 = *flag;
    if (e < E) {
        int s = i64 ? ei[2 * e] : ei[e];
        int d = i64 ? ei[2 * (E + e)] : ei[E + e];
        int pos = atomicAdd(&cursor[d], 1);
        edata[row_ptr[d] + pos] = make_int2(s, __float_as_int(dinv[s]));
    }
}

// ---------- temporal conv1: 8n/block, 4cout x 8s per thread, wave = n ----------
__global__ __launch_bounds__(512, 4) void conv1_kernel(
    const float* __restrict__ x, const float* __restrict__ W1,
    const float* __restrict__ b1, float* __restrict__ h_pre,
    float* __restrict__ psum, float* __restrict__ pss) {
    __shared__ __align__(16) float pool[15360];    // xs[32*288] | w1l[96*64] = 61.4 KB
    float* xs  = pool;                             // [cin][n*36 + s], halo 0 at [32],[35]
    float* w1l = pool + 9216;                      // [kk][cout] (transposed)
    int t = threadIdx.x;
    int grp = blockIdx.x;                          // 512 = b(4) x ngrp(128)
    int b = grp >> 7, n0 = (grp & 127) * 8;
    {   // W1[cout][96] -> w1l[kk][cout]
        int cout = t >> 3, kkb = (t & 7) * 12;
        const float* wsrc = W1 + cout * 96 + kkb;
#pragma unroll
        for (int j = 0; j < 12; j++) w1l[(kkb + j) * 64 + cout] = wsrc[j];
    }
    if (t < 256) {                                 // halo zeros (slots 32..35)
        float* p = xs + (t >> 3) * 288 + (t & 7) * 36 + 32;
        p[0] = 0.f; p[1] = 0.f; p[2] = 0.f; p[3] = 0.f;
    }
#pragma unroll
    for (int i = 0; i < 4; i++) {                  // stage x: 1 KB contiguous per wave
        int flat4 = i * 512 + t;
        int cin = flat4 >> 6;
        int rem = flat4 & 63;
        int n = rem >> 3, s4 = (rem & 7) * 4;
        float4 v = *(const float4*)(x + (((size_t)b * CIN + cin) * NN + n0 + n) * SS + s4);
        *(float4*)(xs + cin * 288 + n * 36 + s4) = v;
    }
    __syncthreads();
    int lane = t & 63, wvi = t >> 6;
    int n = wvi;                                   // one n per wave
    int cout0 = 4 * (lane & 15), s0 = 8 * ((lane >> 4) & 3);
    int m1 = (s0 == 0) ? 35 : (s0 - 1);            // left halo lives at [35]
    float y[4][8];
#pragma unroll
    for (int cc = 0; cc < 4; cc++) {
        float bbv = b1[cout0 + cc];
#pragma unroll
        for (int j = 0; j < 8; j++) y[cc][j] = bbv;
    }
#pragma unroll 4
    for (int cin = 0; cin < CIN; cin++) {
        const float* xr = xs + cin * 288 + n * 36;
        float xw[10];
        xw[0] = xr[m1];
        float4 xa = *(const float4*)(xr + s0);
        float4 xb = *(const float4*)(xr + s0 + 4);
        xw[1] = xa.x; xw[2] = xa.y; xw[3] = xa.z; xw[4] = xa.w;
        xw[5] = xb.x; xw[6] = xb.y; xw[7] = xb.z; xw[8] = xb.w;
        xw[9] = xr[s0 + 8];
        const float* wb = w1l + (3 * cin) * 64 + cout0;
        float4 w0 = *(const float4*)(wb);
        float4 w1v = *(const float4*)(wb + 64);
        float4 w2v = *(const float4*)(wb + 128);
        float wk0[4] = {w0.x, w0.y, w0.z, w0.w};
        float wk1[4] = {w1v.x, w1v.y, w1v.z, w1v.w};
        float wk2[4] = {w2v.x, w2v.y, w2v.z, w2v.w};
#pragma unroll
        for (int cc = 0; cc < 4; cc++)
#pragma unroll
            for (int j = 0; j < 8; j++)
                y[cc][j] += wk0[cc] * xw[j] + wk1[cc] * xw[j + 1] + wk2[cc] * xw[j + 2];
    }
    float* hb = h_pre + (((size_t)(b * NN + n0 + n)) * COUT + cout0) * SS + s0;
#pragma unroll
    for (int cc = 0; cc < 4; cc++) {
        float4 o0 = {y[cc][0], y[cc][1], y[cc][2], y[cc][3]};
        float4 o1 = {y[cc][4], y[cc][5], y[cc][6], y[cc][7]};
        *(float4*)(hb + cc * SS) = o0;
        *(float4*)(hb + cc * SS + 4) = o1;
    }
    float aS[4], aQ[4];
#pragma unroll
    for (int cc = 0; cc < 4; cc++) {
        float s_ = 0.f, q_ = 0.f;
#pragma unroll
        for (int j = 0; j < 8; j++) { s_ += y[cc][j]; q_ += y[cc][j] * y[cc][j]; }
        s_ += __shfl_down(s_, 16); s_ += __shfl_down(s_, 32);
        q_ += __shfl_down(q_, 16); q_ += __shfl_down(q_, 32);
        aS[cc] = s_; aQ[cc] = q_;
    }
    __syncthreads();                               // xs dead -> reuse pool as red
    float* redS = pool;
    float* redQ = pool + 512;
    if (lane < 16) {
#pragma unroll
        for (int cc = 0; cc < 4; cc++) {
            redS[wvi * 64 + 4 * lane + cc] = aS[cc];
            redQ[wvi * 64 + 4 * lane + cc] = aQ[cc];
        }
    }
    __syncthreads();
    if (t < 64) {
        float S = 0.f, Q = 0.f;
#pragma unroll
        for (int w = 0; w < 8; w++) { S += redS[w * 64 + t]; Q += redQ[w * 64 + t]; }
        psum[t * 512 + grp] = S;
        pss[t * 512 + grp] = Q;
    }
}

// ---------- reduce per-block partials -> scale/shift ----------
__global__ void bn_reduce_kernel(const float* __restrict__ psum, const float* __restrict__ pss,
                                 const float* __restrict__ g, const float* __restrict__ be,
                                 float* __restrict__ scale, float* __restrict__ shift,
                                 float invM, int stride, int nslots) {
    int c = blockIdx.x, t = threadIdx.x;    // 64 blocks x 256 threads
    const float* ps = psum + c * stride;
    const float* pq = pss + c * stride;
    float s = 0.f, q = 0.f;
    for (int i = t; i < nslots; i += 256) { s += ps[i]; q += pq[i]; }
#pragma unroll
    for (int o = 32; o > 0; o >>= 1) { s += __shfl_down(s, o); q += __shfl_down(q, o); }
    __shared__ float ws_[4], wq_[4];
    if ((t & 63) == 0) { ws_[t >> 6] = s; wq_[t >> 6] = q; }
    __syncthreads();
    if (t == 0) {
        float S = ws_[0] + ws_[1] + ws_[2] + ws_[3];
        float Q = wq_[0] + wq_[1] + wq_[2] + wq_[3];
        float m = S * invM, v = Q * invM - m * m;
        float sc = g[c] * rsqrtf(v + EPSV);
        scale[c] = sc;
        shift[c] = be[c] - m * sc;
    }
}

// ---------- BN1 apply + ReLU + (h · Wg) -> hw bf16 [B,N,S,C]; 4n/block ----------
__global__ __launch_bounds__(256, 2) void bn1_gemm_kernel(
    const float* __restrict__ h_pre, const float* __restrict__ scale1,
    const float* __restrict__ shift1, const float* __restrict__ Wg,
    ushort* __restrict__ hw) {
    __shared__ __align__(16) float hs[COUT * 144];  // [c][n*36+s], 36.9 KB
    __shared__ __align__(16) float wgl[COUT * CSP]; // 16.4 KB
    int t = threadIdx.x;
    int grp = blockIdx.x;                           // 1024 = b(4) x 256
    int b = grp >> 8, n0 = (grp & 255) * 4;
#pragma unroll
    for (int i = 0; i < 4; i++)
        ((float4*)wgl)[i * 256 + t] = ((const float4*)Wg)[i * 256 + t];
#pragma unroll
    for (int i = 0; i < 8; i++) {
        int flat4 = i * 256 + t;
        int n = flat4 >> 9;
        int rem = flat4 & 511;
        int c = rem >> 3, s4 = (rem & 7) * 4;
        float sc1 = scale1[c], sh1 = shift1[c];
        const float* p = h_pre + (((size_t)(b * NN + n0 + n)) * COUT + c) * SS + s4;
        float4 u = *(const float4*)p;
        float4 v;
        v.x = fmaxf(u.x * sc1 + sh1, 0.f);
        v.y = fmaxf(u.y * sc1 + sh1, 0.f);
        v.z = fmaxf(u.z * sc1 + sh1, 0.f);
        v.w = fmaxf(u.w * sc1 + sh1, 0.f);
        *(float4*)(hs + c * 144 + n * 36 + s4) = v;
    }
    __syncthreads();
    int lane = t & 63, n = t >> 6;
    int d0 = 4 * (lane & 15), s0 = 8 * ((lane >> 4) & 3);
    float acc[4][8];
#pragma unroll
    for (int cc = 0; cc < 4; cc++)
#pragma unroll
        for (int j = 0; j < 8; j++) acc[cc][j] = 0.f;
#pragma unroll 4
    for (int c = 0; c < COUT; c++) {
        float4 w4 = *(const float4*)(wgl + c * 64 + d0);
        const float* xr = hs + c * 144 + n * 36;
        float4 xa = *(const float4*)(xr + s0);
        float4 xb = *(const float4*)(xr + s0 + 4);
        float xv[8] = {xa.x, xa.y, xa.z, xa.w, xb.x, xb.y, xb.z, xb.w};
#pragma unroll
        for (int j = 0; j < 8; j++) {
            acc[0][j] += xv[j] * w4.x;
            acc[1][j] += xv[j] * w4.y;
            acc[2][j] += xv[j] * w4.z;
            acc[3][j] += xv[j] * w4.w;
        }
    }
#pragma unroll
    for (int j = 0; j < 8; j++) {
        uint32_t p0 = f2b_rne(acc[0][j]) | (f2b_rne(acc[1][j]) << 16);
        uint32_t p1 = f2b_rne(acc[2][j]) | (f2b_rne(acc[3][j]) << 16);
        uint2 o = {p0, p1};
        // n-major layout [B,N,S,C]
        *(uint2*)(hw + (((size_t)(b * NN + n0 + n)) * SS + s0 + j) * CSP + d0) = o;
    }
}

// ---------- GCN aggregate v3: whole-row gather, one pass per b ----------
// agg[b,n,:,:] = dn * (sum_src dinv_src*hw[b,src,:,:] + dn*hw[b,n,:,:]) + bg
// 1024 blocks = 4 b x 256 groups of 4 dst nodes; 256 threads; thread owns 16 B of row.
__global__ __launch_bounds__(256, 4) void gcn_kernel(
    const ushort* __restrict__ hw, const int* __restrict__ row_ptr,
    const int2* __restrict__ edata, const float* __restrict__ dinv,
    const float* __restrict__ bg, float* __restrict__ agg,
    float* __restrict__ psum2, float* __restrict__ pss2) {
    int t = threadIdx.x;
    int blk = blockIdx.x;                   // 1024
    int xcd = blk & 7, jj = blk >> 3;       // b-per-XCD-pair locality heuristic
    int b = xcd >> 1;
    int grp = (xcd & 1) + 2 * jj;           // 0..255
    int n0 = grp * 4;
    int off = t * 8;                        // ushort offset within 2048-elem row
    const ushort* hwb = hw + (size_t)b * NN * 2048;
    float bgv[8];
    int c0 = off & 63;
#pragma unroll
    for (int j = 0; j < 8; j++) bgv[j] = bg[c0 + j];
    float sS[8], sQ[8];
#pragma unroll
    for (int j = 0; j < 8; j++) { sS[j] = 0.f; sQ[j] = 0.f; }
    for (int g = 0; g < 4; g++) {
        int n = n0 + g;
        int r0 = row_ptr[n], r1 = row_ptr[n + 1];
        float dn = dinv[n];
        float acc[8];
        {   // self row, weight dn
            uint4 u = *(const uint4*)(hwb + (size_t)n * 2048 + off);
            acc[0] = dn * bfu(u.x); acc[1] = dn * bfh(u.x);
            acc[2] = dn * bfu(u.y); acc[3] = dn * bfh(u.y);
            acc[4] = dn * bfu(u.z); acc[5] = dn * bfh(u.z);
            acc[6] = dn * bfu(u.w); acc[7] = dn * bfh(u.w);
        }
        int r = r0;
        for (; r + 2 <= r1; r += 2) {       // 2 rows in flight
            int2 e0 = edata[r], e1 = edata[r + 1];
            uint4 u0 = *(const uint4*)(hwb + (size_t)e0.x * 2048 + off);
            uint4 u1 = *(const uint4*)(hwb + (size_t)e1.x * 2048 + off);
            float w0 = __int_as_float(e0.y), w1 = __int_as_float(e1.y);
            acc[0] += w0 * bfu(u0.x) + w1 * bfu(u1.x);
            acc[1] += w0 * bfh(u0.x) + w1 * bfh(u1.x);
            acc[2] += w0 * bfu(u0.y) + w1 * bfu(u1.y);
            acc[3] += w0 * bfh(u0.y) + w1 * bfh(u1.y);
            acc[4] += w0 * bfu(u0.z) + w1 * bfu(u1.z);
            acc[5] += w0 * bfh(u0.z) + w1 * bfh(u1.z);
            acc[6] += w0 * bfu(u0.w) + w1 * bfu(u1.w);
            acc[7] += w0 * bfh(u0.w) + w1 * bfh(u1.w);
        }
        if (r < r1) {
            int2 e = edata[r];
            uint4 u = *(const uint4*)(hwb + (size_t)e.x * 2048 + off);
            float w = __int_as_float(e.y);
            acc[0] += w * bfu(u.x); acc[1] += w * bfh(u.x);
            acc[2] += w * bfu(u.y); acc[3] += w * bfh(u.y);
            acc[4] += w * bfu(u.z); acc[5] += w * bfh(u.z);
            acc[6] += w * bfu(u.w); acc[7] += w * bfh(u.w);
        }
        float o[8];
#pragma unroll
        for (int j = 0; j < 8; j++) {
            o[j] = dn * acc[j] + bgv[j];
            sS[j] += o[j]; sQ[j] += o[j] * o[j];
        }
        float* ar = agg + ((size_t)(b * NN + n)) * 2048 + off;
        float4 o0 = {o[0], o[1], o[2], o[3]}, o1 = {o[4], o[5], o[6], o[7]};
        *(float4*)ar = o0; *(float4*)(ar + 4) = o1;
    }
    float* ps = psum2 + ((size_t)(b * 256 + grp)) * 2048 + off;
    float* pq = pss2 + ((size_t)(b * 256 + grp)) * 2048 + off;
    float4 s0v = {sS[0], sS[1], sS[2], sS[3]}, s1v = {sS[4], sS[5], sS[6], sS[7]};
    float4 q0v = {sQ[0], sQ[1], sQ[2], sQ[3]}, q1v = {sQ[4], sQ[5], sQ[6], sQ[7]};
    *(float4*)ps = s0v; *(float4*)(ps + 4) = s1v;
    *(float4*)pq = q0v; *(float4*)(pq + 4) = q1v;
}

// ---------- BN2: reduce 256 group-partials per (b,s,c) -> scale2/shift2 ----------
__global__ void bn2_reduce_kernel(const float* __restrict__ psum2, const float* __restrict__ pss2,
                                  const float* __restrict__ gs, const float* __restrict__ bes,
                                  float* __restrict__ scale2, float* __restrict__ shift2) {
    int idx = blockIdx.x * 256 + threadIdx.x;   // 8192 = B*S*C
    int b = idx >> 11, rem = idx & 2047;
    const float* ps = psum2 + (size_t)b * 256 * 2048 + rem;
    const float* pq = pss2 + (size_t)b * 256 * 2048 + rem;
    float S = 0.f, Q = 0.f;
    for (int g = 0; g < 256; g++) { S += ps[(size_t)g * 2048]; Q += pq[(size_t)g * 2048]; }
    int d = idx & 63;
    float m = S * (1.f / NN);
    float v = Q * (1.f / NN) - m * m;
    float sc = gs[d] * rsqrtf(v + EPSV);
    scale2[idx] = sc;
    shift2[idx] = bes[d] - m * sc;
}

// ---------- BN2+ReLU + conv2: 8n/block, cin-halved LDS, reg accumulators ----------
__global__ __launch_bounds__(512, 4) void conv2_kernel(
    const float* __restrict__ agg, const float* __restrict__ scale2,
    const float* __restrict__ shift2, const float* __restrict__ W2,
    const float* __restrict__ b2, float* __restrict__ h2_pre,
    float* __restrict__ psum, float* __restrict__ pss) {
    __shared__ __align__(16) float pool[15360];    // ts[32*288] | w2l[96*64] = 61.4 KB
    float* ts  = pool;                             // [cinL][n*36+s]
    float* w2l = pool + 9216;                      // [kkL][cout]
    int t = threadIdx.x;
    int grp = blockIdx.x;                          // 512 = b(4) x ngrp(128)
    int b = grp >> 7, n0 = (grp & 127) * 8;
    int s_st = (t >> 3) & 31;                      // staging s (const per thread)
    int c4_st = t & 7;                             // staging c-quad
    if (t < 256) {                                 // halo zeros (persist across halves)
        float* p = ts + (t >> 3) * 288 + (t & 7) * 36 + 32;
        p[0] = 0.f; p[1] = 0.f; p[2] = 0.f; p[3] = 0.f;
    }
    int lane = t & 63, wvi = t >> 6;
    int n = wvi;
    int cout0 = 4 * (lane & 15), s0 = 8 * ((lane >> 4) & 3);
    int m1 = (s0 == 0) ? 35 : (s0 - 1);
    float y[4][8];
#pragma unroll
    for (int cc = 0; cc < 4; cc++) {
        float bbv = b2[cout0 + cc];
#pragma unroll
        for (int j = 0; j < 8; j++) y[cc][j] = bbv;
    }
    for (int half = 0; half < 2; half++) {
        __syncthreads();                           // prev compute done / halos published
        {   // stage weight half: kk in [half*96, half*96+96)
            int cout = t >> 3, kkb = (t & 7) * 12;
            const float* wsrc = W2 + cout * 192 + half * 96 + kkb;
#pragma unroll
            for (int j = 0; j < 12; j++) w2l[(kkb + j) * 64 + cout] = wsrc[j];
        }
        {   // stage activation half from agg[B,N,S,C] with BN2+ReLU
            int c0 = half * 32 + 4 * c4_st;
            int bsi = b * SS + s_st;
            float4 sc = *(const float4*)(scale2 + bsi * 64 + c0);
            float4 sh = *(const float4*)(shift2 + bsi * 64 + c0);
            int cL = 4 * c4_st;
#pragma unroll
            for (int i = 0; i < 4; i++) {
                int nn_ = 2 * i + (t >> 8);
                float4 u = *(const float4*)(agg +
                    (((size_t)(b * NN + n0 + nn_)) * SS + s_st) * CSP + c0);
                float* dst = ts + cL * 288 + nn_ * 36 + s_st;
                dst[0]   = fmaxf(u.x * sc.x + sh.x, 0.f);
                dst[288] = fmaxf(u.y * sc.y + sh.y, 0.f);
                dst[576] = fmaxf(u.z * sc.z + sh.z, 0.f);
                dst[864] = fmaxf(u.w * sc.w + sh.w, 0.f);
            }
        }
        __syncthreads();
#pragma unroll 4
        for (int cl = 0; cl < 32; cl++) {
            const float* xr = ts + cl * 288 + n * 36;
            float xw[10];
            xw[0] = xr[m1];
            float4 xa = *(const float4*)(xr + s0);
            float4 xb = *(const float4*)(xr + s0 + 4);
            xw[1] = xa.x; xw[2] = xa.y; xw[3] = xa.z; xw[4] = xa.w;
            xw[5] = xb.x; xw[6] = xb.y; xw[7] = xb.z; xw[8] = xb.w;
            xw[9] = xr[s0 + 8];
            const float* wb = w2l + (3 * cl) * 64 + cout0;
            float4 w0 = *(const float4*)(wb);
            float4 w1v = *(const float4*)(wb + 64);
            float4 w2v = *(const float4*)(wb + 128);
            float wk0[4] = {w0.x, w0.y, w0.z, w0.w};
            float wk1[4] = {w1v.x, w1v.y, w1v.z, w1v.w};
            float wk2[4] = {w2v.x, w2v.y, w2v.z, w2v.w};
#pragma unroll
            for (int cc = 0; cc < 4; cc++)
#pragma unroll
                for (int j = 0; j < 8; j++)
                    y[cc][j] += wk0[cc] * xw[j] + wk1[cc] * xw[j + 1] + wk2[cc] * xw[j + 2];
        }
    }
    float* hb = h2_pre + (((size_t)(b * NN + n0 + n)) * COUT + cout0) * SS + s0;
#pragma unroll
    for (int cc = 0; cc < 4; cc++) {
        float4 o0 = {y[cc][0], y[cc][1], y[cc][2], y[cc][3]};
        float4 o1 = {y[cc][4], y[cc][5], y[cc][6], y[cc][7]};
        *(float4*)(hb + cc * SS) = o0;
        *(float4*)(hb + cc * SS + 4) = o1;
    }
    float aS[4], aQ[4];
#pragma unroll
    for (int cc = 0; cc < 4; cc++) {
        float s_ = 0.f, q_ = 0.f;
#pragma unroll
        for (int j = 0; j < 8; j++) { s_ += y[cc][j]; q_ += y[cc][j] * y[cc][j]; }
        s_ += __shfl_down(s_, 16); s_ += __shfl_down(s_, 32);
        q_ += __shfl_down(q_, 16); q_ += __shfl_down(q_, 32);
        aS[cc] = s_; aQ[cc] = q_;
    }
    __syncthreads();                               // ts dead -> reuse pool
    float* redS = pool;
    float* redQ = pool + 512;
    if (lane < 16) {
#pragma unroll
        for (int cc = 0; cc < 4; cc++) {
            redS[wvi * 64 + 4 * lane + cc] = aS[cc];
            redQ[wvi * 64 + 4 * lane + cc] = aQ[cc];
        }
    }
    __syncthreads();
    if (t < 64) {
        float S = 0.f, Q = 0.f;
#pragma unroll
        for (int w = 0; w < 8; w++) { S += redS[w * 64 + t]; Q += redQ[w * 64 + t]; }
        psum[t * 512 + grp] = S;
        pss[t * 512 + grp] = Q;
    }
}

// ---------- final: BN3+ReLU + residual 1x1 conv + ReLU, write [B,Cout,N,S] ----------
__global__ __launch_bounds__(256) void final_kernel(
    const float* __restrict__ x, const float* __restrict__ Wres,
    const float* __restrict__ bres, const float* __restrict__ h2_pre,
    const float* __restrict__ scale3, const float* __restrict__ shift3,
    float* __restrict__ out) {
    __shared__ __align__(16) float xs[CIN][36];
    __shared__ float wrl[COUT * 33];
    int t = threadIdx.x;
    int bn = blockIdx.x;
    int b = bn >> 10, n = bn & (NN - 1);
    {
        int sst = t & 31, cinb = t >> 5;            // bank 2-way
#pragma unroll
        for (int i = 0; i < 4; i++) {
            int cin = cinb + 8 * i;
            xs[cin][sst] = x[(((size_t)b * CIN + cin) * NN + n) * SS + sst];
        }
    }
#pragma unroll
    for (int i = 0; i < 2; i++) {
        int lin = (i * 256 + t) * 4;                // rows of 32
        int cw = lin >> 5, c0 = lin & 31;
        float4 v = *(const float4*)(Wres + lin);
        float* dst = &wrl[cw * 33 + c0];
        dst[0] = v.x; dst[1] = v.y; dst[2] = v.z; dst[3] = v.w;
    }
    __syncthreads();
    int cout = t >> 2, s0 = (t & 3) * 8;
    float res[8];
    float bb = bres[cout];
#pragma unroll
    for (int j = 0; j < 8; j++) res[j] = bb;
    const float* wrow = &wrl[cout * 33];
#pragma unroll 4
    for (int cin = 0; cin < CIN; cin++) {
        float w = wrow[cin];
        float4 xa = *(const float4*)&xs[cin][s0];
        float4 xb = *(const float4*)&xs[cin][s0 + 4];
        res[0] += xa.x * w; res[1] += xa.y * w; res[2] += xa.z * w; res[3] += xa.w * w;
        res[4] += xb.x * w; res[5] += xb.y * w; res[6] += xb.z * w; res[7] += xb.w * w;
    }
    const float* hp = h2_pre + (size_t)bn * COUT * SS + cout * SS + s0;
    float4 h0 = *(const float4*)hp, h1 = *(const float4*)(hp + 4);
    float h2[8] = {h0.x, h0.y, h0.z, h0.w, h1.x, h1.y, h1.z, h1.w};
    float sc = scale3[cout], sh = shift3[cout];
    float o[8];
#pragma unroll
    for (int j = 0; j < 8; j++) {
        float hv = fmaxf(sc * h2[j] + sh, 0.f);
        o[j] = fmaxf(hv + res[j], 0.f);
    }
    float* op = out + (((size_t)b * COUT + cout) * NN + n) * SS + s0;
    float4 o0 = {o[0], o[1], o[2], o[3]}, o1 = {o[4], o[5], o[6], o[7]};
    *(float4*)op = o0; *(float4*)(op + 4) = o1;
}

// ---------- host ----------
extern "C" void kernel_launch(void* const* d_in, const int* in_sizes, int n_in,
                              void* d_out, int out_size, void* d_ws, size_t ws_size,
                              hipStream_t stream) {
    const float* x    = (const float*)d_in[0];
    const int*   ei   = (const int*)  d_in[1];
    const float* W1   = (const float*)d_in[2];
    const float* b1   = (const float*)d_in[3];
    const float* g1   = (const float*)d_in[4];
    const float* be1  = (const float*)d_in[5];
    const float* Wg   = (const float*)d_in[6];
    const float* bg   = (const float*)d_in[7];
    const float* gs   = (const float*)d_in[8];
    const float* bes  = (const float*)d_in[9];
    const float* W2   = (const float*)d_in[10];
    const float* b2   = (const float*)d_in[11];
    const float* g2   = (const float*)d_in[12];
    const float* be2  = (const float*)d_in[13];
    const float* Wres = (const float*)d_in[14];
    const float* bres = (const float*)d_in[15];
    float* out = (float*)d_out;
    int E = in_sizes[1] / 2;

    char* ws = (char*)d_ws;
    // zeroed region: [0, 8192)
    int*   deg    = (int*)  (ws + 0);            // 4096 B
    int*   cursor = (int*)  (ws + 4096);         // 4096 B
    int*   row_ptr= (int*)  (ws + 73728);        // 4100 B
    int*   flag   = (int*)  (ws + 77888);        // 4 B
    float* dinv   = (float*)(ws + 78080);        // 4096 B
    float* scale1 = (float*)(ws + 82176);        // 256 B each
    float* shift1 = (float*)(ws + 82432);
    float* scale3 = (float*)(ws + 82688);
    float* shift3 = (float*)(ws + 82944);
    float* scale2 = (float*)(ws + 83200);        // 32768 B
    float* shift2 = (float*)(ws + 115968);       // 32768 B -> 148736
    float* psum   = (float*)(ws + 148736);       // 131072 B (64 ch x 512 slots)
    float* pss    = (float*)(ws + 279808);       // 131072 B -> 410880
    int2*  edata  = (int2*) (ws + 410880);       // 8*E = 131072 B -> 541952 (+768 pad)
    char*  bigA   = ws + 542720;                 // 33.55 MB region
    // bigA usage: [0, 16.78M) = hw bf16; upper half = psum2/pss2 during gcn,
    // whole region = h2_pre fp32 from conv2 on (psum2 consumed by then).
    ushort* hwB   = (ushort*)bigA;
    float* psum2  = (float*)(bigA + 16777216);   // 8.39 MB
    float* pss2   = (float*)(bigA + 25165824);   // 8.39 MB
    float* h2p    = (float*)bigA;
    // d_out doubles as scratch: h_pre (conv1 out), then agg (gcn out).
    float* h_pre  = out;
    float* agg    = out;

    hipMemsetAsync(ws, 0, 8192, stream);
    detect_kernel<<<1, 64, 0, stream>>>(ei, flag);
    int egrid = (E + 255) / 256;
    deg_count_kernel<<<egrid, 256, 0, stream>>>(ei, E, flag, deg);
    scan_kernel<<<1, NN, 0, stream>>>(deg, row_ptr, dinv);
    csr_fill_kernel<<<egrid, 256, 0, stream>>>(ei, E, flag, row_ptr, cursor, dinv, edata);

    conv1_kernel<<<512, 512, 0, stream>>>(x, W1, b1, h_pre, psum, pss);
    bn_reduce_kernel<<<64, 256, 0, stream>>>(psum, pss, g1, be1, scale1, shift1,
                                             1.f / (B_ * NN * SS), 512, 512);
    bn1_gemm_kernel<<<1024, 256, 0, stream>>>(h_pre, scale1, shift1, Wg, hwB);
    gcn_kernel<<<1024, 256, 0, stream>>>(hwB, row_ptr, edata, dinv, bg, agg, psum2, pss2);
    bn2_reduce_kernel<<<32, 256, 0, stream>>>(psum2, pss2, gs, bes, scale2, shift2);
    conv2_kernel<<<512, 512, 0, stream>>>(agg, scale2, shift2, W2, b2, h2p, psum, pss);
    bn_reduce_kernel<<<64, 256, 0, stream>>>(psum, pss, g2, be2, scale3, shift3,
                                             1.f / (B_ * NN * SS), 512, 512);
    final_kernel<<<B_ * NN, 256, 0, stream>>>(x, Wres, bres, h2p, scale3, shift3, out);
}